// Round 5
// baseline (144.530 us; speedup 1.0000x reference)
//
#include <hip/hip_runtime.h>
#include <math.h>

// KAN layer forward, MI355X.
// NUM_IN = NUM_OUT = 128, SIZE = 16384, BATCH = 512, K = 3 (cubic), G = 5.
//
// Reference semantics:
//   s = o*128 + i ;  pre_acts[s,b]   = x[b,i]
//   post_splines[s,b] = mask[s] * sum_j coef[s,j] * B3_j(x[b,i]; grid_s)
//   post_acts[s,b]    = scale_b[s]*silu(x[b,i]) + scale_spline[s]*post_splines[s,b]
//   y[b,i] = sum_o post_acts[o*128+i, b]
// Outputs concatenated: y (512*128), pre_acts.T, post_splines.T, post_acts.T
// (each 512*16384, layout [b][s]).
//
// v5 = v4 (127 us: 2048 blocks, prefetched param chunks, cndmask-tree coef
// select, scalar NT stores) + ONE structural change:
//   - block now owns ALL 128 o for (1 batch x 32 i). y[b,i] completes inside
//     the block: LDS-reduce 8 o-octant partials -> ONE plain store per element.
//     Removes all 2M device-scope atomics (32 serialized per y address at L2)
//     and the hipMemsetAsync dispatch. silu/x-load now 1x per thread (was 4x).
//   - per-cell math, store pattern, load pattern otherwise identical to v4.

#define N_IN   128
#define SIZEK  16384

__global__ __launch_bounds__(256) void kan_fwd(
    const float* __restrict__ x,            // [512][128]
    const float* __restrict__ scale_b,      // [16384]
    const float* __restrict__ scale_spline, // [16384]
    const float* __restrict__ coef,         // [16384][8]
    const float* __restrict__ mask,         // [16384]
    const float* __restrict__ knots,        // [16384][6]
    float* __restrict__ y,                  // [512][128]
    float* __restrict__ pre_out,            // [512][16384]
    float* __restrict__ spl_out,            // [512][16384]
    float* __restrict__ post_out)           // [512][16384]
{
    const int tid = threadIdx.x;
    const int di  = tid & 31;        // i within the block's 32-wide i-slice
    const int oct = tid >> 5;        // o-octant (0..7), 16 o each
    const int ig  = blockIdx.x & 3;  // i-group (4 groups of 32)
    const int b   = blockIdx.x >> 2; // batch (512)
    const int i   = (ig << 5) | di;

    const float xx  = x[b * N_IN + i];
    const float sil = xx / (1.0f + __expf(-xx));   // silu(x) = x * sigmoid(x)
    float ysum = 0.0f;

#pragma unroll 1   // keep VGPR low: one 4-row param chunk in flight at a time
    for (int oc4 = 0; oc4 < 4; ++oc4) {
        const int o0 = (oct << 4) | (oc4 << 2);    // this thread's o-chunk base

        // ---- prefetch 4 param rows (independent loads -> one waitcnt batch)
        float e0v[4], ihv[4], mkv[4], sbv[4], ssv[4];
        float4 cAv[4], cBv[4];
#pragma unroll
        for (int oo = 0; oo < 4; ++oo) {
            const int s = ((o0 + oo) << 7) | i;
            const float k0 = knots[s * 6];
            const float k5 = knots[s * 6 + 5];
            const float h  = (k5 - k0) * 0.2f;     // (g_last-g_first)/G, G=5
            ihv[oo] = 1.0f / h;
            e0v[oo] = k0 - 3.0f * h;               // leftmost extended knot
            mkv[oo] = mask[s];
            sbv[oo] = scale_b[s];
            ssv[oo] = scale_spline[s];
            const float4* c4 = (const float4*)(coef + (size_t)s * 8);
            cAv[oo] = c4[0];
            cBv[oo] = c4[1];
        }

#pragma unroll
        for (int oo = 0; oo < 4; ++oo) {
            const int s = ((o0 + oo) << 7) | i;
            const float e0   = e0v[oo];
            const float invh = ihv[oo];
            // 8 coefficients register-resident; selected via cndmask tree.
            const float c0 = cAv[oo].x, c1 = cAv[oo].y, c2 = cAv[oo].z, c3 = cAv[oo].w;
            const float c4 = cBv[oo].x, c5 = cBv[oo].y, c6 = cBv[oo].z, c7 = cBv[oo].w;

            const float u  = (xx - e0) * invh;
            const float mf = floorf(u);
            const int   m  = (int)mf;
            const float tt = u - mf;                // fractional position
            const bool inr = (m >= 0) && (m <= 10); // inside extended grid?

            const float t2  = tt * tt;
            const float t3  = t2 * tt;
            const float omt = 1.0f - tt;
            float w[4];
            w[0] = omt * omt * omt * (1.0f / 6.0f);
            w[1] = (3.0f * t3 - 6.0f * t2 + 4.0f) * (1.0f / 6.0f);
            w[2] = (-3.0f * t3 + 3.0f * t2 + 3.0f * tt + 1.0f) * (1.0f / 6.0f);
            w[3] = t3 * (1.0f / 6.0f);

            const int jlo = m - 3;
            float spline = 0.0f;
#pragma unroll
            for (int rr = 0; rr < 4; ++rr) {
                const int j  = jlo + rr;
                const int jc = min(max(j, 0), 7);   // clamped select index
                const float s01   = (jc & 1) ? c1 : c0;
                const float s23   = (jc & 1) ? c3 : c2;
                const float s45   = (jc & 1) ? c5 : c4;
                const float s67   = (jc & 1) ? c7 : c6;
                const float s0123 = (jc & 2) ? s23 : s01;
                const float s4567 = (jc & 2) ? s67 : s45;
                const float c     = (jc & 4) ? s4567 : s0123;
                const float wv = (inr && j >= 0 && j <= 7) ? w[rr] : 0.0f;
                spline = fmaf(c, wv, spline);
            }

            const float splm = spline * mkv[oo];
            const float post = fmaf(sbv[oo], sil, ssv[oo] * splm);

            const size_t idx = (size_t)b * SIZEK + (size_t)s;
            __builtin_nontemporal_store(xx,   &pre_out[idx]);
            __builtin_nontemporal_store(splm, &spl_out[idx]);
            __builtin_nontemporal_store(post, &post_out[idx]);
            ysum += post;
        }
    }

    // ---- y[b, i] = sum over 8 o-octants, all within this block. No atomics.
    __shared__ float red[8][33];     // +1 pad: conflict-free write & read
    red[oct][di] = ysum;
    __syncthreads();
    if (tid < 32) {
        float a = 0.0f;
#pragma unroll
        for (int d = 0; d < 8; ++d)
            a += red[d][tid];
        y[b * N_IN + (ig << 5) + tid] = a;   // plain full-overwrite store
    }
}

extern "C" void kernel_launch(void* const* d_in, const int* in_sizes, int n_in,
                              void* d_out, int out_size, void* d_ws, size_t ws_size,
                              hipStream_t stream) {
    const float* x            = (const float*)d_in[0];
    const float* scale_b      = (const float*)d_in[1];
    const float* scale_spline = (const float*)d_in[2];
    const float* coef         = (const float*)d_in[3];
    const float* mask         = (const float*)d_in[4];
    const float* knots        = (const float*)d_in[5];

    float* out  = (float*)d_out;
    float* y    = out;                         // 512*128      = 65536
    float* pre  = y + 512 * 128;               // 512*16384    = 8388608
    float* spl  = pre + (size_t)512 * 16384;
    float* post = spl + (size_t)512 * 16384;

    // blocks: 512 batches x 4 i-groups = 2048; 256 threads each.
    // y fully overwritten by kan_fwd (no atomics, no memset needed).
    dim3 grid(2048), block(256);
    kan_fwd<<<grid, block, 0, stream>>>(x, scale_b, scale_spline, coef, mask,
                                        knots, y, pre, spl, post);
}

// Round 6
// 125.940 us; speedup vs baseline: 1.1476x; 1.1476x over previous
//
#include <hip/hip_runtime.h>
#include <math.h>

// KAN layer forward, MI355X.
// NUM_IN = NUM_OUT = 128, SIZE = 16384, BATCH = 512, K = 3 (cubic), G = 5.
//
// Reference semantics:
//   s = o*128 + i ;  pre_acts[s,b]   = x[b,i]
//   post_splines[s,b] = mask[s] * sum_j coef[s,j] * B3_j(x[b,i]; grid_s)
//   post_acts[s,b]    = scale_b[s]*silu(x[b,i]) + scale_spline[s]*post_splines[s,b]
//   y[b,i] = sum_o post_acts[o*128+i, b]
// Outputs concatenated: y (512*128), pre_acts.T, post_splines.T, post_acts.T
// (each 512*16384, layout [b][s]).
//
// v6 = v4 (127.2 us best-known: 2048 blocks, prefetched param chunks,
// cndmask-tree coef select) with ONE change:
//   - plain stores instead of nontemporal. The harness fill kernel hits
//     6.2 TB/s with plain stores THROUGH L2 (L2 acts as a write-combining
//     buffer streaming full lines to HBM); our nt-flagged scalar stores
//     bypass L2 and sustained only ~2.9 TB/s. NT was bundled into v2 with
//     the occupancy fix and never ablated — ablating it now.
// v5 lesson: removing the y atomics at structural cost REGRESSED (144 us);
// atomics are not the dominant residual. Keep v4's atomic tail.

#define N_IN   128
#define SIZEK  16384
#define BATCH  512

#define TB 4    // batches per thread
#define CO 4    // o-values per thread

__global__ __launch_bounds__(256) void kan_fwd(
    const float* __restrict__ x,            // [512][128]
    const float* __restrict__ scale_b,      // [16384]
    const float* __restrict__ scale_spline, // [16384]
    const float* __restrict__ coef,         // [16384][8]
    const float* __restrict__ mask,         // [16384]
    const float* __restrict__ knots,        // [16384][6]
    float* __restrict__ y,                  // [512][128] (pre-zeroed)
    float* __restrict__ pre_out,            // [512][16384]
    float* __restrict__ spl_out,            // [512][16384]
    float* __restrict__ post_out)           // [512][16384]
{
    const int g  = blockIdx.x * blockDim.x + threadIdx.x;
    const int i  = g & 127;          // input index (lane-consecutive -> coalesced)
    const int r  = g >> 7;
    const int oc = r & 31;           // o-chunk id (32 chunks of 4)
    const int bg = r >> 5;           // batch-group id (128 groups of 4)
    const int o0 = oc << 2;
    const int b0 = bg << 2;

    float xv[TB], sil[TB], ysum[TB];
#pragma unroll
    for (int t = 0; t < TB; ++t) {
        const float xx = x[(b0 + t) * N_IN + i];
        xv[t]   = xx;
        sil[t]  = xx / (1.0f + __expf(-xx));   // silu(x) = x * sigmoid(x)
        ysum[t] = 0.0f;
    }

    // ---- prefetch all CO param rows (independent loads -> one waitcnt batch)
    float e0v[CO], ihv[CO], mkv[CO], sbv[CO], ssv[CO];
    float4 cA[CO], cB[CO];
#pragma unroll
    for (int oo = 0; oo < CO; ++oo) {
        const int s = ((o0 + oo) << 7) | i;
        const float k0 = knots[s * 6];
        const float k5 = knots[s * 6 + 5];
        const float h  = (k5 - k0) * 0.2f;     // (g_last-g_first)/G, G=5
        ihv[oo] = 1.0f / h;
        e0v[oo] = k0 - 3.0f * h;               // leftmost extended knot
        mkv[oo] = mask[s];
        sbv[oo] = scale_b[s];
        ssv[oo] = scale_spline[s];
        const float4* c4 = (const float4*)(coef + (size_t)s * 8);
        cA[oo] = c4[0];
        cB[oo] = c4[1];
    }

#pragma unroll
    for (int oo = 0; oo < CO; ++oo) {
        const int s = ((o0 + oo) << 7) | i;
        const float e0   = e0v[oo];
        const float invh = ihv[oo];
        const float mk   = mkv[oo];
        const float sb   = sbv[oo];
        const float ss   = ssv[oo];
        // 8 coefficients live in registers; selected via cndmask tree below.
        const float c0 = cA[oo].x, c1 = cA[oo].y, c2 = cA[oo].z, c3 = cA[oo].w;
        const float c4 = cB[oo].x, c5 = cB[oo].y, c6 = cB[oo].z, c7 = cB[oo].w;

#pragma unroll
        for (int t = 0; t < TB; ++t) {
            const float u  = (xv[t] - e0) * invh;
            const float mf = floorf(u);
            const int   m  = (int)mf;
            const float tt = u - mf;               // fractional position in interval
            const bool inr = (m >= 0) && (m <= 10); // inside extended grid?

            const float t2  = tt * tt;
            const float t3  = t2 * tt;
            const float omt = 1.0f - tt;
            float w[4];
            w[0] = omt * omt * omt * (1.0f / 6.0f);
            w[1] = (3.0f * t3 - 6.0f * t2 + 4.0f) * (1.0f / 6.0f);
            w[2] = (-3.0f * t3 + 3.0f * t2 + 3.0f * tt + 1.0f) * (1.0f / 6.0f);
            w[3] = t3 * (1.0f / 6.0f);

            const int jlo = m - 3;
            float spline = 0.0f;
#pragma unroll
            for (int rr = 0; rr < 4; ++rr) {
                const int j  = jlo + rr;
                const int jc = min(max(j, 0), 7);   // clamped select index
                // register-only 8->1 select by bits of jc (7 cndmask, no scratch)
                const float s01   = (jc & 1) ? c1 : c0;
                const float s23   = (jc & 1) ? c3 : c2;
                const float s45   = (jc & 1) ? c5 : c4;
                const float s67   = (jc & 1) ? c7 : c6;
                const float s0123 = (jc & 2) ? s23 : s01;
                const float s4567 = (jc & 2) ? s67 : s45;
                const float c     = (jc & 4) ? s4567 : s0123;
                const float wv = (inr && j >= 0 && j <= 7) ? w[rr] : 0.0f;
                spline = fmaf(c, wv, spline);
            }

            const float splm = spline * mk;
            const float post = fmaf(sb, sil[t], ss * splm);

            const size_t idx = (size_t)(b0 + t) * SIZEK + (size_t)s;
            pre_out[idx]  = xv[t];
            spl_out[idx]  = splm;
            post_out[idx] = post;
            ysum[t] += post;
        }
    }

#pragma unroll
    for (int t = 0; t < TB; ++t)
        atomicAdd(&y[(b0 + t) * N_IN + i], ysum[t]);
}

extern "C" void kernel_launch(void* const* d_in, const int* in_sizes, int n_in,
                              void* d_out, int out_size, void* d_ws, size_t ws_size,
                              hipStream_t stream) {
    const float* x            = (const float*)d_in[0];
    const float* scale_b      = (const float*)d_in[1];
    const float* scale_spline = (const float*)d_in[2];
    const float* coef         = (const float*)d_in[3];
    const float* mask         = (const float*)d_in[4];
    const float* knots        = (const float*)d_in[5];

    float* out  = (float*)d_out;
    float* y    = out;                         // 512*128      = 65536
    float* pre  = y + 512 * 128;               // 512*16384    = 8388608
    float* spl  = pre + (size_t)512 * 16384;
    float* post = spl + (size_t)512 * 16384;

    // y is accumulated with atomics; harness poisons d_out with 0xAA.
    (void)hipMemsetAsync(y, 0, 512 * 128 * sizeof(float), stream);

    // threads = 128 i * 32 o-chunks * 128 b-groups = 524288 -> 2048 blocks
    dim3 grid(2048), block(256);
    kan_fwd<<<grid, block, 0, stream>>>(x, scale_b, scale_spline, coef, mask,
                                        knots, y, pre, spl, post);
}

// Round 7
// 121.592 us; speedup vs baseline: 1.1886x; 1.0358x over previous
//
#include <hip/hip_runtime.h>
#include <math.h>

// KAN layer forward, MI355X.
// NUM_IN = NUM_OUT = 128, SIZE = 16384, BATCH = 512, K = 3 (cubic), G = 5.
//
// Reference semantics:
//   s = o*128 + i ;  pre_acts[s,b]   = x[b,i]
//   post_splines[s,b] = mask[s] * sum_j coef[s,j] * B3_j(x[b,i]; grid_s)
//   post_acts[s,b]    = scale_b[s]*silu(x[b,i]) + scale_spline[s]*post_splines[s,b]
//   y[b,i] = sum_o post_acts[o*128+i, b]
// Outputs concatenated: y (512*128), pre_acts.T, post_splines.T, post_acts.T
// (each 512*16384, layout [b][s]).
//
// v7 = v6 (125.9 us best-known: 2048 blocks, prefetched param chunks,
// cndmask-tree coef select, PLAIN stores, atomic y-tail) + ONE change:
//   - wave-uniform-grid fast path: if all 4 prefetched rows share
//     (e0, invh) — true for this problem's inputs, where knots is a tiled
//     linspace — hoist the basis computation (u, m, w[4], range masks,
//     clamped select indices) to once per batch t and reuse across the
//     4 o-chunks. Cuts per-cell VALU ~80 -> ~45 instrs. Slow path = v6
//     verbatim, so the kernel stays correct for arbitrary knots.
// History: v5 (block-wide y reduce) regressed — atomics are cheap; v3b
// (per-lane coef gathers) regressed — line-divergent gathers choke TA.

#define N_IN   128
#define SIZEK  16384
#define BATCH  512

#define TB 4    // batches per thread
#define CO 4    // o-values per thread

__global__ __launch_bounds__(256) void kan_fwd(
    const float* __restrict__ x,            // [512][128]
    const float* __restrict__ scale_b,      // [16384]
    const float* __restrict__ scale_spline, // [16384]
    const float* __restrict__ coef,         // [16384][8]
    const float* __restrict__ mask,         // [16384]
    const float* __restrict__ knots,        // [16384][6]
    float* __restrict__ y,                  // [512][128] (pre-zeroed)
    float* __restrict__ pre_out,            // [512][16384]
    float* __restrict__ spl_out,            // [512][16384]
    float* __restrict__ post_out)           // [512][16384]
{
    const int g  = blockIdx.x * blockDim.x + threadIdx.x;
    const int i  = g & 127;          // input index (lane-consecutive -> coalesced)
    const int r  = g >> 7;
    const int oc = r & 31;           // o-chunk id (32 chunks of 4)
    const int bg = r >> 5;           // batch-group id (128 groups of 4)
    const int o0 = oc << 2;
    const int b0 = bg << 2;

    float xv[TB], sil[TB], ysum[TB];
#pragma unroll
    for (int t = 0; t < TB; ++t) {
        const float xx = x[(b0 + t) * N_IN + i];
        xv[t]   = xx;
        sil[t]  = xx / (1.0f + __expf(-xx));   // silu(x) = x * sigmoid(x)
        ysum[t] = 0.0f;
    }

    // ---- prefetch all CO param rows (independent loads -> one waitcnt batch)
    float e0v[CO], ihv[CO], mkv[CO], sbv[CO], ssv[CO];
    float4 cA[CO], cB[CO];
#pragma unroll
    for (int oo = 0; oo < CO; ++oo) {
        const int s = ((o0 + oo) << 7) | i;
        const float k0 = knots[s * 6];
        const float k5 = knots[s * 6 + 5];
        const float h  = (k5 - k0) * 0.2f;     // (g_last-g_first)/G, G=5
        ihv[oo] = 1.0f / h;
        e0v[oo] = k0 - 3.0f * h;               // leftmost extended knot
        mkv[oo] = mask[s];
        sbv[oo] = scale_b[s];
        ssv[oo] = scale_spline[s];
        const float4* c4 = (const float4*)(coef + (size_t)s * 8);
        cA[oo] = c4[0];
        cB[oo] = c4[1];
    }

    // wave-uniform check: do all 4 rows share the same (e0, invh)?
    const bool same_lane =
        (e0v[1] == e0v[0]) && (ihv[1] == ihv[0]) &&
        (e0v[2] == e0v[0]) && (ihv[2] == ihv[0]) &&
        (e0v[3] == e0v[0]) && (ihv[3] == ihv[0]);

    if (__all(same_lane)) {
        // ======== FAST PATH: basis hoisted across the CO o-chunks ========
        const float e0   = e0v[0];
        const float invh = ihv[0];
#pragma unroll
        for (int t = 0; t < TB; ++t) {
            const float u  = (xv[t] - e0) * invh;
            const float mf = floorf(u);
            const int   m  = (int)mf;
            const float tt = u - mf;
            const bool inr = (m >= 0) && (m <= 10);

            const float t2  = tt * tt;
            const float t3  = t2 * tt;
            const float omt = 1.0f - tt;
            float w[4];
            w[0] = omt * omt * omt * (1.0f / 6.0f);
            w[1] = (3.0f * t3 - 6.0f * t2 + 4.0f) * (1.0f / 6.0f);
            w[2] = (-3.0f * t3 + 3.0f * t2 + 3.0f * tt + 1.0f) * (1.0f / 6.0f);
            w[3] = t3 * (1.0f / 6.0f);

            // masked weights + clamped select indices, once per t
            const int jlo = m - 3;
            int   jc[4];
            float wv[4];
#pragma unroll
            for (int rr = 0; rr < 4; ++rr) {
                const int j = jlo + rr;
                jc[rr] = min(max(j, 0), 7);
                wv[rr] = (inr && j >= 0 && j <= 7) ? w[rr] : 0.0f;
            }

#pragma unroll
            for (int oo = 0; oo < CO; ++oo) {
                const int s = ((o0 + oo) << 7) | i;
                const float c0 = cA[oo].x, c1 = cA[oo].y, c2 = cA[oo].z, c3 = cA[oo].w;
                const float c4 = cB[oo].x, c5 = cB[oo].y, c6 = cB[oo].z, c7 = cB[oo].w;

                float spline = 0.0f;
#pragma unroll
                for (int rr = 0; rr < 4; ++rr) {
                    const int jcr = jc[rr];
                    const float s01   = (jcr & 1) ? c1 : c0;
                    const float s23   = (jcr & 1) ? c3 : c2;
                    const float s45   = (jcr & 1) ? c5 : c4;
                    const float s67   = (jcr & 1) ? c7 : c6;
                    const float s0123 = (jcr & 2) ? s23 : s01;
                    const float s4567 = (jcr & 2) ? s67 : s45;
                    const float c     = (jcr & 4) ? s4567 : s0123;
                    spline = fmaf(c, wv[rr], spline);
                }

                const float splm = spline * mkv[oo];
                const float post = fmaf(sbv[oo], sil[t], ssv[oo] * splm);

                const size_t idx = (size_t)(b0 + t) * SIZEK + (size_t)s;
                pre_out[idx]  = xv[t];
                spl_out[idx]  = splm;
                post_out[idx] = post;
                ysum[t] += post;
            }
        }
    } else {
        // ======== SLOW PATH: v6 verbatim (general knots) ========
#pragma unroll
        for (int oo = 0; oo < CO; ++oo) {
            const int s = ((o0 + oo) << 7) | i;
            const float e0   = e0v[oo];
            const float invh = ihv[oo];
            const float mk   = mkv[oo];
            const float sb   = sbv[oo];
            const float ss   = ssv[oo];
            const float c0 = cA[oo].x, c1 = cA[oo].y, c2 = cA[oo].z, c3 = cA[oo].w;
            const float c4 = cB[oo].x, c5 = cB[oo].y, c6 = cB[oo].z, c7 = cB[oo].w;

#pragma unroll
            for (int t = 0; t < TB; ++t) {
                const float u  = (xv[t] - e0) * invh;
                const float mf = floorf(u);
                const int   m  = (int)mf;
                const float tt = u - mf;
                const bool inr = (m >= 0) && (m <= 10);

                const float t2  = tt * tt;
                const float t3  = t2 * tt;
                const float omt = 1.0f - tt;
                float w[4];
                w[0] = omt * omt * omt * (1.0f / 6.0f);
                w[1] = (3.0f * t3 - 6.0f * t2 + 4.0f) * (1.0f / 6.0f);
                w[2] = (-3.0f * t3 + 3.0f * t2 + 3.0f * tt + 1.0f) * (1.0f / 6.0f);
                w[3] = t3 * (1.0f / 6.0f);

                const int jlo = m - 3;
                float spline = 0.0f;
#pragma unroll
                for (int rr = 0; rr < 4; ++rr) {
                    const int j  = jlo + rr;
                    const int jcr = min(max(j, 0), 7);
                    const float s01   = (jcr & 1) ? c1 : c0;
                    const float s23   = (jcr & 1) ? c3 : c2;
                    const float s45   = (jcr & 1) ? c5 : c4;
                    const float s67   = (jcr & 1) ? c7 : c6;
                    const float s0123 = (jcr & 2) ? s23 : s01;
                    const float s4567 = (jcr & 2) ? s67 : s45;
                    const float c     = (jcr & 4) ? s4567 : s0123;
                    const float wvv = (inr && j >= 0 && j <= 7) ? w[rr] : 0.0f;
                    spline = fmaf(c, wvv, spline);
                }

                const float splm = spline * mk;
                const float post = fmaf(sb, sil[t], ss * splm);

                const size_t idx = (size_t)(b0 + t) * SIZEK + (size_t)s;
                pre_out[idx]  = xv[t];
                spl_out[idx]  = splm;
                post_out[idx] = post;
                ysum[t] += post;
            }
        }
    }

#pragma unroll
    for (int t = 0; t < TB; ++t)
        atomicAdd(&y[(b0 + t) * N_IN + i], ysum[t]);
}

extern "C" void kernel_launch(void* const* d_in, const int* in_sizes, int n_in,
                              void* d_out, int out_size, void* d_ws, size_t ws_size,
                              hipStream_t stream) {
    const float* x            = (const float*)d_in[0];
    const float* scale_b      = (const float*)d_in[1];
    const float* scale_spline = (const float*)d_in[2];
    const float* coef         = (const float*)d_in[3];
    const float* mask         = (const float*)d_in[4];
    const float* knots        = (const float*)d_in[5];

    float* out  = (float*)d_out;
    float* y    = out;                         // 512*128      = 65536
    float* pre  = y + 512 * 128;               // 512*16384    = 8388608
    float* spl  = pre + (size_t)512 * 16384;
    float* post = spl + (size_t)512 * 16384;

    // y is accumulated with atomics; harness poisons d_out with 0xAA.
    (void)hipMemsetAsync(y, 0, 512 * 128 * sizeof(float), stream);

    // threads = 128 i * 32 o-chunks * 128 b-groups = 524288 -> 2048 blocks
    dim3 grid(2048), block(256);
    kan_fwd<<<grid, block, 0, stream>>>(x, scale_b, scale_spline, coef, mask,
                                        knots, y, pre, spl, post);
}

// Round 8
// 121.184 us; speedup vs baseline: 1.1926x; 1.0034x over previous
//
#include <hip/hip_runtime.h>
#include <math.h>

// KAN layer forward, MI355X.
// NUM_IN = NUM_OUT = 128, SIZE = 16384, BATCH = 512, K = 3 (cubic), G = 5.
//
// Reference semantics:
//   s = o*128 + i ;  pre_acts[s,b]   = x[b,i]
//   post_splines[s,b] = mask[s] * sum_j coef[s,j] * B3_j(x[b,i]; grid_s)
//   post_acts[s,b]    = scale_b[s]*silu(x[b,i]) + scale_spline[s]*post_splines[s,b]
//   y[b,i] = sum_o post_acts[o*128+i, b]
// Outputs concatenated: y (512*128), pre_acts.T, post_splines.T, post_acts.T
// (each 512*16384, layout [b][s]).
//
// v8 = v7 (121.6 us: wave-uniform-grid fast path, plain stores, atomic
// y-tail, 2048 blocks) + ONE mechanism change:
//   - coef moves from per-thread registers (28-cndmask select tree/cell +
//     8 line-divergent float4 prefetches/thread) to LDS with row stride 9
//     (coprime with 32 banks -> ds_read addresses 9*lane+jc are
//     conflict-free). Window select becomes 4 computed-address
//     ds_read_b32 per cell on the otherwise-idle LDS pipe.
//   - blocks remapped so each block covers ONE oc-chunk (512 consecutive
//     s-rows) x 8 batches; same grid size, same store coalescing.
// History: v3b (inner-loop global coef gathers) regressed -> TA choke;
// v5 (block y-reduce) regressed -> atomics cheap; v6 NT ablation won.

#define N_IN   128
#define SIZEK  16384
#define BATCH  512

#define TB 4    // batches per thread
#define CO 4    // o-values per thread
#define CPAD 9  // padded coef row stride in LDS (gcd(9,32)=1 -> conflict-free)

__global__ __launch_bounds__(256) void kan_fwd(
    const float* __restrict__ x,            // [512][128]
    const float* __restrict__ scale_b,      // [16384]
    const float* __restrict__ scale_spline, // [16384]
    const float* __restrict__ coef,         // [16384][8]
    const float* __restrict__ mask,         // [16384]
    const float* __restrict__ knots,        // [16384][6]
    float* __restrict__ y,                  // [512][128] (pre-zeroed)
    float* __restrict__ pre_out,            // [512][16384]
    float* __restrict__ spl_out,            // [512][16384]
    float* __restrict__ post_out)           // [512][16384]
{
    __shared__ float shc[512 * CPAD];       // 18432 B -> still 8 blocks/CU

    const int tid = threadIdx.x;
    const int g  = blockIdx.x * 256 + tid;
    const int i  = g & 127;          // input index (lane-consecutive -> coalesced)
    const int r  = g >> 7;           // [0, 4096)
    const int oc = r >> 7;           // o-chunk id, BLOCK-UNIFORM (32 chunks of 4 o)
    const int bg = r & 127;          // batch-group id (128 groups of 4)
    const int o0 = oc << 2;
    const int b0 = bg << 2;
    const int s_base = o0 << 7;      // first of the block's 512 consecutive s-rows

    // ---- stage the block's coef rows into LDS (coalesced float4 reads,
    //      padded-stride b32 writes). One-time cost per block.
    {
        const float4* src = (const float4*)(coef + (size_t)s_base * 8); // 1024 vec4
#pragma unroll
        for (int k = 0; k < 4; ++k) {
            const int f4  = k * 256 + tid;        // [0,1024)
            const float4 v = src[f4];
            const int row = f4 >> 1;              // [0,512)
            const int col = (f4 & 1) << 2;        // 0 or 4
            float* d = &shc[row * CPAD + col];
            d[0] = v.x; d[1] = v.y; d[2] = v.z; d[3] = v.w;
        }
    }

    float xv[TB], sil[TB], ysum[TB];
#pragma unroll
    for (int t = 0; t < TB; ++t) {
        const float xx = x[(b0 + t) * N_IN + i];
        xv[t]   = xx;
        sil[t]  = xx / (1.0f + __expf(-xx));   // silu(x) = x * sigmoid(x)
        ysum[t] = 0.0f;
    }

    // ---- prefetch per-edge scalars for the CO rows (independent loads)
    float e0v[CO], ihv[CO], mkv[CO], sbv[CO], ssv[CO];
#pragma unroll
    for (int oo = 0; oo < CO; ++oo) {
        const int s = ((o0 + oo) << 7) | i;
        const float k0 = knots[s * 6];
        const float k5 = knots[s * 6 + 5];
        const float h  = (k5 - k0) * 0.2f;     // (g_last-g_first)/G, G=5
        ihv[oo] = 1.0f / h;
        e0v[oo] = k0 - 3.0f * h;               // leftmost extended knot
        mkv[oo] = mask[s];
        sbv[oo] = scale_b[s];
        ssv[oo] = scale_spline[s];
    }

    __syncthreads();                 // coef staging complete (uniform barrier)

    // wave-uniform check: do all 4 rows share the same (e0, invh)?
    const bool same_lane =
        (e0v[1] == e0v[0]) && (ihv[1] == ihv[0]) &&
        (e0v[2] == e0v[0]) && (ihv[2] == ihv[0]) &&
        (e0v[3] == e0v[0]) && (ihv[3] == ihv[0]);

    if (__all(same_lane)) {
        // ======== FAST PATH: basis hoisted across the CO o-chunks ========
        const float e0   = e0v[0];
        const float invh = ihv[0];
#pragma unroll
        for (int t = 0; t < TB; ++t) {
            const float u  = (xv[t] - e0) * invh;
            const float mf = floorf(u);
            const int   m  = (int)mf;
            const float tt = u - mf;
            const bool inr = (m >= 0) && (m <= 10);

            const float t2  = tt * tt;
            const float t3  = t2 * tt;
            const float omt = 1.0f - tt;
            float w[4];
            w[0] = omt * omt * omt * (1.0f / 6.0f);
            w[1] = (3.0f * t3 - 6.0f * t2 + 4.0f) * (1.0f / 6.0f);
            w[2] = (-3.0f * t3 + 3.0f * t2 + 3.0f * tt + 1.0f) * (1.0f / 6.0f);
            w[3] = t3 * (1.0f / 6.0f);

            // masked weights + clamped select indices, once per t
            const int jlo = m - 3;
            int   jc[4];
            float wv[4];
#pragma unroll
            for (int rr = 0; rr < 4; ++rr) {
                const int j = jlo + rr;
                jc[rr] = min(max(j, 0), 7);
                wv[rr] = (inr && j >= 0 && j <= 7) ? w[rr] : 0.0f;
            }

#pragma unroll
            for (int oo = 0; oo < CO; ++oo) {
                const int s = ((o0 + oo) << 7) | i;
                const float* __restrict__ cs = &shc[(oo * 128 + i) * CPAD];

                float spline = 0.0f;
#pragma unroll
                for (int rr = 0; rr < 4; ++rr)
                    spline = fmaf(cs[jc[rr]], wv[rr], spline);  // ds_read_b32

                const float splm = spline * mkv[oo];
                const float post = fmaf(sbv[oo], sil[t], ssv[oo] * splm);

                const size_t idx = (size_t)(b0 + t) * SIZEK + (size_t)s;
                pre_out[idx]  = xv[t];
                spl_out[idx]  = splm;
                post_out[idx] = post;
                ysum[t] += post;
            }
        }
    } else {
        // ======== SLOW PATH: per-oo basis (general knots), LDS coef ========
#pragma unroll
        for (int oo = 0; oo < CO; ++oo) {
            const int s = ((o0 + oo) << 7) | i;
            const float e0   = e0v[oo];
            const float invh = ihv[oo];
            const float mk   = mkv[oo];
            const float sb   = sbv[oo];
            const float ss   = ssv[oo];
            const float* __restrict__ cs = &shc[(oo * 128 + i) * CPAD];

#pragma unroll
            for (int t = 0; t < TB; ++t) {
                const float u  = (xv[t] - e0) * invh;
                const float mf = floorf(u);
                const int   m  = (int)mf;
                const float tt = u - mf;
                const bool inr = (m >= 0) && (m <= 10);

                const float t2  = tt * tt;
                const float t3  = t2 * tt;
                const float omt = 1.0f - tt;
                float w[4];
                w[0] = omt * omt * omt * (1.0f / 6.0f);
                w[1] = (3.0f * t3 - 6.0f * t2 + 4.0f) * (1.0f / 6.0f);
                w[2] = (-3.0f * t3 + 3.0f * t2 + 3.0f * tt + 1.0f) * (1.0f / 6.0f);
                w[3] = t3 * (1.0f / 6.0f);

                const int jlo = m - 3;
                float spline = 0.0f;
#pragma unroll
                for (int rr = 0; rr < 4; ++rr) {
                    const int j   = jlo + rr;
                    const int jcr = min(max(j, 0), 7);
                    const float wvv = (inr && j >= 0 && j <= 7) ? w[rr] : 0.0f;
                    spline = fmaf(cs[jcr], wvv, spline);
                }

                const float splm = spline * mk;
                const float post = fmaf(sb, sil[t], ss * splm);

                const size_t idx = (size_t)(b0 + t) * SIZEK + (size_t)s;
                pre_out[idx]  = xv[t];
                spl_out[idx]  = splm;
                post_out[idx] = post;
                ysum[t] += post;
            }
        }
    }

#pragma unroll
    for (int t = 0; t < TB; ++t)
        atomicAdd(&y[(b0 + t) * N_IN + i], ysum[t]);
}

extern "C" void kernel_launch(void* const* d_in, const int* in_sizes, int n_in,
                              void* d_out, int out_size, void* d_ws, size_t ws_size,
                              hipStream_t stream) {
    const float* x            = (const float*)d_in[0];
    const float* scale_b      = (const float*)d_in[1];
    const float* scale_spline = (const float*)d_in[2];
    const float* coef         = (const float*)d_in[3];
    const float* mask         = (const float*)d_in[4];
    const float* knots        = (const float*)d_in[5];

    float* out  = (float*)d_out;
    float* y    = out;                         // 512*128      = 65536
    float* pre  = y + 512 * 128;               // 512*16384    = 8388608
    float* spl  = pre + (size_t)512 * 16384;
    float* post = spl + (size_t)512 * 16384;

    // y is accumulated with atomics; harness poisons d_out with 0xAA.
    (void)hipMemsetAsync(y, 0, 512 * 128 * sizeof(float), stream);

    // threads = 128 i * 32 o-chunks * 128 b-groups = 524288 -> 2048 blocks
    dim3 grid(2048), block(256);
    kan_fwd<<<grid, block, 0, stream>>>(x, scale_b, scale_spline, coef, mask,
                                        knots, y, pre, spl, post);
}